// Round 4
// baseline (280.711 us; speedup 1.0000x reference)
//
#include <hip/hip_runtime.h>

// B=1048576, A=3, N=8, NUM_CLASSES=3, LAMBDA_COORD=5
#define B_SIZE  1048576
#define NBLK    2048             // 2048 blocks x 4 waves = 8192 waves, 2 tiles each
#define NWAVE   (NBLK * 4)       // 8192
#define TSTRIDE (NWAVE * 64)     // 524288 batches between a wave's two tiles

__device__ __forceinline__ float frcp(float x) { return __builtin_amdgcn_rcpf(x); }

// R4: discriminating experiment for the latency-stall hypothesis.
// R2 (coalesced, 20 waves/CU) = 102us; R3 (ILP but uncoalesced) = 120us.
// This kernel keeps R2's EXACT coalesced load pattern (float4, lane-contiguous,
// 1KB/instr) and R2's LDS transpose, but gives each wave TWO tiles with both
// tiles' global loads issued before any math -> tile-1 loads fly under tile-0
// math (counted vmcnt waits instead of full drain per tile).
__device__ __forceinline__ float tile_process(
    float4 (*__restrict__ buf)[8],            // wave-private [64][8] LDS
    const float4* __restrict__ vp,            // 6 pred float4s (load order)
    const float4* __restrict__ vg,            // 8 gt float4s (load order)
    const int4 c0, const int4 c1, const int lane) {
    // ---- pred transpose through LDS (6 b128 writes + 6 b128 reads) ----
    #pragma unroll
    for (int k = 0; k < 6; ++k) {
        const unsigned f  = k * 64 + lane;          // float4 idx in 64x6 slab
        const unsigned bl = f / 6u, of = f % 6u;    // magic-mul, constant divisor
        buf[bl][of ^ (bl & 7u)] = vp[k];
    }
    float pr[24];
    #pragma unroll
    for (int s = 0; s < 6; ++s) {
        const float4 t = buf[lane][s ^ (lane & 7)];
        pr[s*4+0] = t.x; pr[s*4+1] = t.y; pr[s*4+2] = t.z; pr[s*4+3] = t.w;
    }
    // ---- gt transpose through the SAME buffer (WAR-safe: wave-private,
    //      DS unit is in-order per wave) ----
    #pragma unroll
    for (int k = 0; k < 8; ++k) {
        const unsigned f  = k * 64 + lane;
        const unsigned bl = f >> 3, of = f & 7;
        buf[bl][of ^ (bl & 7u)] = vg[k];
    }
    float gb[32];
    #pragma unroll
    for (int s = 0; s < 8; ++s) {
        const float4 t = buf[lane][s ^ (lane & 7)];
        gb[s*4+0] = t.x; gb[s*4+1] = t.y; gb[s*4+2] = t.z; gb[s*4+3] = t.w;
    }
    const int gc[8] = {c0.x, c0.y, c0.z, c0.w, c1.x, c1.y, c1.z, c1.w};

    // ---- per-anchor loss math (R2-validated, unchanged numerics) ----
    float total = 0.0f;
    #pragma unroll
    for (int a = 0; a < 3; ++a) {
        const float* p = pr + a * 8;
        const float px = frcp(1.0f + __expf(-p[0]));
        const float py = frcp(1.0f + __expf(-p[1]));
        const float pw = p[2];
        const float ph = p[3];
        const float z  = p[4];
        const float px1 = px - pw * 0.5f, px2 = px + pw * 0.5f;
        const float py1 = py - ph * 0.5f, py2 = py + ph * 0.5f;
        const float pa_eps = (px2 - px1) * (py2 - py1) + 1e-6f;

        float best_iou = -3.4e38f;
        int best_idx = 0;
        #pragma unroll
        for (int n = 0; n < 8; ++n) {
            const float gx = gb[n*4+0], gy = gb[n*4+1];
            const float gw = gb[n*4+2], gh = gb[n*4+3];
            const float hw = gw * 0.5f, hh = gh * 0.5f;
            const float iw = fmaxf(fminf(px2, gx + hw) - fmaxf(px1, gx - hw), 0.0f);
            const float ih = fmaxf(fminf(py2, gy + hh) - fmaxf(py1, gy - hh), 0.0f);
            const float inter = iw * ih;
            const float iou = inter * frcp((pa_eps + gw * gh) - inter);
            const bool upd = iou > best_iou;       // strict > == first-max (argmax)
            best_iou = upd ? iou : best_iou;
            best_idx = upd ? n : best_idx;
        }
        const bool matched = best_iou > 0.5f;

        float mbx = gb[0], mby = gb[1], mbw = gb[2], mbh = gb[3];
        int mcls = gc[0];
        #pragma unroll
        for (int n = 1; n < 8; ++n) {
            const bool s = (best_idx == n);
            mbx = s ? gb[n*4+0] : mbx;
            mby = s ? gb[n*4+1] : mby;
            mbw = s ? gb[n*4+2] : mbw;
            mbh = s ? gb[n*4+3] : mbh;
            mcls = s ? gc[n] : mcls;
        }

        // conf loss via shared softplus (clamped):
        const float az = fabsf(z);
        const float c  = __logf(1.0f + __expf(-az));
        const float sp_pos = fmaxf(z, 0.0f) + c;
        const float sp_neg = fmaxf(-z, 0.0f) + c;
        total += fminf(matched ? sp_neg : sp_pos, 100.0f);

        if (matched) {
            const float dx = px - mbx, dy = py - mby;
            const float dw = pw - mbw, dh = ph - mbh;
            total += 5.0f * (dx*dx + dy*dy + dw*dw + dh*dh);
            const float l0 = p[5], l1 = p[6], l2 = p[7];
            const float m = fmaxf(l0, fmaxf(l1, l2));
            const float lse = m + __logf(__expf(l0-m) + __expf(l1-m) + __expf(l2-m));
            const float sel = (mcls == 0) ? l0 : ((mcls == 1) ? l1 : l2);
            total += lse - sel;
        }
    }
    return total;
}

__device__ __forceinline__ float wave_reduce(float v) {
    #pragma unroll
    for (int off = 32; off > 0; off >>= 1)
        v += __shfl_down(v, off, 64);
    return v;
}

__global__ __launch_bounds__(256) void yolo_loss_kernel(
    const float* __restrict__ pred,       // [B,3,8]  row = 24 floats
    const float* __restrict__ gt_boxes,   // [B,8,4]  row = 32 floats
    const int*   __restrict__ gt_classes, // [B,8]    row = 8 ints
    double* __restrict__ part) {          // [NWAVE] per-wave partials (no atomics)
    __shared__ float4 sBuf[4][64][8];     // 32 KB/block -> 5 blocks/CU LDS-wise

    const int tid  = threadIdx.x;
    const int wave = tid >> 6;
    const int lane = tid & 63;
    const int wid  = blockIdx.x * 4 + wave;   // 0..8191
    const int wb0  = wid * 64;                // tile-0 wave batch base
    const int wb1  = wb0 + TSTRIDE;           // tile-1 wave batch base

    // ---- issue BOTH tiles' loads up front, fully coalesced (1 KB/instr) ----
    const float4* pA0 = reinterpret_cast<const float4*>(pred     + (size_t)wb0 * 24);
    const float4* gA0 = reinterpret_cast<const float4*>(gt_boxes + (size_t)wb0 * 32);
    const float4* pA1 = reinterpret_cast<const float4*>(pred     + (size_t)wb1 * 24);
    const float4* gA1 = reinterpret_cast<const float4*>(gt_boxes + (size_t)wb1 * 32);
    float4 vp0[6], vg0[8], vp1[6], vg1[8];
    #pragma unroll
    for (int k = 0; k < 6; ++k) vp0[k] = pA0[k * 64 + lane];
    #pragma unroll
    for (int k = 0; k < 8; ++k) vg0[k] = gA0[k * 64 + lane];
    #pragma unroll
    for (int k = 0; k < 6; ++k) vp1[k] = pA1[k * 64 + lane];
    #pragma unroll
    for (int k = 0; k < 8; ++k) vg1[k] = gA1[k * 64 + lane];
    // classes: 2-KB contiguous per wave, 2 instrs per tile
    const int4* cme0 = reinterpret_cast<const int4*>(gt_classes + (size_t)(wb0 + lane) * 8);
    const int4* cme1 = reinterpret_cast<const int4*>(gt_classes + (size_t)(wb1 + lane) * 8);
    const int4 c00 = cme0[0], c01 = cme0[1];
    const int4 c10 = cme1[0], c11 = cme1[1];

    float4 (*buf)[8] = sBuf[wave];

    // tile 0: consumes vp0/vg0 (vmcnt counted wait); tile-1 loads stay in flight
    double dacc = (double)wave_reduce(tile_process(buf, vp0, vg0, c00, c01, lane));
    // tile 1: loads have had the whole tile-0 math phase (~1400 cyc) to land
    dacc += (double)wave_reduce(tile_process(buf, vp1, vg1, c10, c11, lane));

    if (lane == 0)
        part[wid] = dacc;
}

__global__ __launch_bounds__(256) void yolo_reduce_kernel(
    const double* __restrict__ part, float* __restrict__ out) {
    double s = 0.0;
    #pragma unroll
    for (int k = 0; k < NWAVE / 256; ++k)
        s += part[threadIdx.x + k * 256];      // coalesced
    #pragma unroll
    for (int off = 32; off > 0; off >>= 1)
        s += __shfl_down(s, off, 64);
    __shared__ double r[4];
    const int lane = threadIdx.x & 63;
    const int wave = threadIdx.x >> 6;
    if (lane == 0) r[wave] = s;
    __syncthreads();
    if (threadIdx.x == 0)
        out[0] = (float)((r[0] + r[1] + r[2] + r[3]) / (double)B_SIZE);
}

extern "C" void kernel_launch(void* const* d_in, const int* in_sizes, int n_in,
                              void* d_out, int out_size, void* d_ws, size_t ws_size,
                              hipStream_t stream) {
    const float* pred       = (const float*)d_in[0];
    const float* gt_boxes   = (const float*)d_in[1];
    const int*   gt_classes = (const int*)d_in[2];
    float* out   = (float*)d_out;
    double* part = (double*)d_ws;   // 8192 doubles = 64 KB scratch; every slot
                                    // written each launch (poison-safe)

    yolo_loss_kernel<<<NBLK, 256, 0, stream>>>(pred, gt_boxes, gt_classes, part);
    yolo_reduce_kernel<<<1, 256, 0, stream>>>(part, out);
}

// Round 5
// 278.747 us; speedup vs baseline: 1.0070x; 1.0070x over previous
//
#include <hip/hip_runtime.h>

// B=1048576, A=3, N=8, NUM_CLASSES=3, LAMBDA_COORD=5
#define B_SIZE 1048576
#define NBLK   4096            // 256 thr/block, 64 batches/wave, 1 tile/wave
#define NWAVE  (NBLK * 4)      // 16384 per-wave partials

__device__ __forceinline__ float frcp(float x) { return __builtin_amdgcn_rcpf(x); }

// R5: code-size experiment. R0-R4 pinned at ~102-120us with ALL throughput
// counters <25% and insensitivity to occupancy (8 vs 20 waves/CU) and to
// data prefetch (R4). Remaining candidate: instruction delivery — the fully
// unrolled body is ~16-35 KB of straight-line code; phase-staggered waves
// thrash the shared icache and stream code from L2 (time ~ dynamic
// instruction-line fetches, matching R0=R2=R4 and R3 exactly). Fix: ROLL the
// loops. Dynamic register indexing would spill (rule #20), so batch rows now
// LIVE in LDS through the math and are runtime-indexed there. Static code
// shrinks ~6-8x.
__global__ __launch_bounds__(256) void yolo_loss_kernel(
    const float* __restrict__ pred,       // [B,3,8]  row = 24 floats
    const float* __restrict__ gt_boxes,   // [B,8,4]  row = 32 floats
    const int*   __restrict__ gt_classes, // [B,8]    row = 8 ints
    double* __restrict__ part) {          // [NWAVE] per-wave partials
    // Per-wave [64][16] float4 rows (256 B): slots 0-5 pred, 6-13 gt,
    // 14-15 classes (8 ints bit-cast). XOR slot swizzle s^(row&15) keeps 16-B
    // alignment and spreads quarter-wave same-slot reads across banks (2-way
    // = free). 4 waves x 16 KB = 65536 B/block (static LDS limit) -> 2
    // blocks/CU; R0 proved 2 blocks/CU performs identically to 5 here.
    __shared__ float4 sBuf[4][64][16];

    const int tid  = threadIdx.x;
    const int wave = tid >> 6;
    const int lane = tid & 63;
    const int wid  = blockIdx.x * 4 + wave;
    const int wb   = wid * 64;            // wave's batch base

    // ---- coalesced global loads (1 KB/instr), unchanged from R2 ----
    const float4* pA = reinterpret_cast<const float4*>(pred     + (size_t)wb * 24);
    const float4* gA = reinterpret_cast<const float4*>(gt_boxes + (size_t)wb * 32);
    float4 vp[6], vg[8];
    #pragma unroll
    for (int k = 0; k < 6; ++k) vp[k] = pA[k * 64 + lane];
    #pragma unroll
    for (int k = 0; k < 8; ++k) vg[k] = gA[k * 64 + lane];
    const int4* cme = reinterpret_cast<const int4*>(gt_classes + (size_t)(wb + lane) * 8);
    const int4 c0 = cme[0], c1 = cme[1];

    float4 (*buf)[16] = sBuf[wave];
    const unsigned rx = lane & 15;        // this lane's row XOR key

    // ---- stage into LDS (14 b128 writes + 2 class writes); rows wave-private,
    //      DS unit is in-order per wave, no barrier needed ----
    #pragma unroll
    for (int k = 0; k < 6; ++k) {
        const unsigned f = k * 64 + lane, bl = f / 6u, of = f % 6u;
        buf[bl][of ^ (bl & 15u)] = vp[k];
    }
    #pragma unroll
    for (int k = 0; k < 8; ++k) {
        const unsigned f = k * 64 + lane, bl = f >> 3, of = f & 7;
        buf[bl][(6 + of) ^ (bl & 15u)] = vg[k];
    }
    buf[lane][14 ^ rx] = make_float4(__int_as_float(c0.x), __int_as_float(c0.y),
                                     __int_as_float(c0.z), __int_as_float(c0.w));
    buf[lane][15 ^ rx] = make_float4(__int_as_float(c1.x), __int_as_float(c1.y),
                                     __int_as_float(c1.z), __int_as_float(c1.w));

    const float4* row = buf[lane];

    // ---- per-anchor loss math: ROLLED anchor loop (R2-validated numerics) ----
    float total = 0.0f;
    #pragma unroll 1
    for (int a = 0; a < 3; ++a) {
        const float4 q0 = row[(2 * a)     ^ rx];   // p[0..3]
        const float4 q1 = row[(2 * a + 1) ^ rx];   // p[4..7]
        const float px = frcp(1.0f + __expf(-q0.x));
        const float py = frcp(1.0f + __expf(-q0.y));
        const float pw = q0.z;
        const float ph = q0.w;
        const float z  = q1.x;
        const float px1 = px - pw * 0.5f, px2 = px + pw * 0.5f;
        const float py1 = py - ph * 0.5f, py2 = py + ph * 0.5f;
        const float pa_eps = (px2 - px1) * (py2 - py1) + 1e-6f;

        float best_iou = -3.4e38f;
        int best_idx = 0;
        #pragma unroll 2
        for (int n = 0; n < 8; ++n) {
            const float4 g = row[(6 + n) ^ rx];    // one dynamic b128 read/box
            const float hw = g.z * 0.5f, hh = g.w * 0.5f;
            const float iw = fmaxf(fminf(px2, g.x + hw) - fmaxf(px1, g.x - hw), 0.0f);
            const float ih = fmaxf(fminf(py2, g.y + hh) - fmaxf(py1, g.y - hh), 0.0f);
            const float inter = iw * ih;
            const float iou = inter * frcp((pa_eps + g.z * g.w) - inter);
            const bool upd = iou > best_iou;       // strict > == first-max (argmax)
            best_iou = upd ? iou : best_iou;
            best_idx = upd ? n : best_idx;
        }
        const bool matched = best_iou > 0.5f;

        // matched box + class: single dynamic LDS reads (replaces select chain)
        const float4 mb = row[(6 + best_idx) ^ rx];
        const float* rowf = reinterpret_cast<const float*>(row);
        const int cslot = (14 + (best_idx >> 2)) ^ rx;
        const int mcls  = __float_as_int(rowf[cslot * 4 + (best_idx & 3)]);

        // conf loss via shared softplus (clamped):
        const float az = fabsf(z);
        const float c  = __logf(1.0f + __expf(-az));
        const float sp_pos = fmaxf(z, 0.0f) + c;
        const float sp_neg = fmaxf(-z, 0.0f) + c;
        total += fminf(matched ? sp_neg : sp_pos, 100.0f);

        if (matched) {
            const float dx = px - mb.x, dy = py - mb.y;
            const float dw = pw - mb.z, dh = ph - mb.w;
            total += 5.0f * (dx*dx + dy*dy + dw*dw + dh*dh);
            const float l0 = q1.y, l1 = q1.z, l2 = q1.w;
            const float m = fmaxf(l0, fmaxf(l1, l2));
            const float lse = m + __logf(__expf(l0-m) + __expf(l1-m) + __expf(l2-m));
            const float sel = (mcls == 0) ? l0 : ((mcls == 1) ? l1 : l2);
            total += lse - sel;
        }
    }

    // ---- wave(64) shuffle reduce -> per-wave partial (no atomics) ----
    #pragma unroll
    for (int off = 32; off > 0; off >>= 1)
        total += __shfl_down(total, off, 64);
    if (lane == 0)
        part[wid] = (double)total;
}

__global__ __launch_bounds__(256) void yolo_reduce_kernel(
    const double* __restrict__ part, float* __restrict__ out) {
    double s = 0.0;
    #pragma unroll 8
    for (int k = 0; k < NWAVE / 256; ++k)
        s += part[threadIdx.x + k * 256];      // coalesced
    #pragma unroll
    for (int off = 32; off > 0; off >>= 1)
        s += __shfl_down(s, off, 64);
    __shared__ double r[4];
    const int lane = threadIdx.x & 63;
    const int wave = threadIdx.x >> 6;
    if (lane == 0) r[wave] = s;
    __syncthreads();
    if (threadIdx.x == 0)
        out[0] = (float)((r[0] + r[1] + r[2] + r[3]) / (double)B_SIZE);
}

extern "C" void kernel_launch(void* const* d_in, const int* in_sizes, int n_in,
                              void* d_out, int out_size, void* d_ws, size_t ws_size,
                              hipStream_t stream) {
    const float* pred       = (const float*)d_in[0];
    const float* gt_boxes   = (const float*)d_in[1];
    const int*   gt_classes = (const int*)d_in[2];
    float* out   = (float*)d_out;
    double* part = (double*)d_ws;   // 16384 doubles = 128 KB scratch; every slot
                                    // written each launch (poison-safe)

    yolo_loss_kernel<<<NBLK, 256, 0, stream>>>(pred, gt_boxes, gt_classes, part);
    yolo_reduce_kernel<<<1, 256, 0, stream>>>(part, out);
}

// Round 6
// 277.482 us; speedup vs baseline: 1.0116x; 1.0046x over previous
//
#include <hip/hip_runtime.h>

// B=1048576, A=3, N=8, NUM_CLASSES=3, LAMBDA_COORD=5
#define B_SIZE 1048576
#define NBLK   4096            // 256 thr/block, 64 batches/wave
#define NWAVE  (NBLK * 4)      // 16384 per-wave partials

__device__ __forceinline__ float frcp(float x) { return __builtin_amdgcn_rcpf(x); }

// R6: WORK-REDUCTION experiment. R0-R5 pinned at ~102us invariant to occupancy,
// ILP, coalescing, code size, and even data residency (L3-hot replays = same
// time); only R3 (more instrs/wave) was slower. Surviving model: time ~ total
// dynamic instructions at a fixed low effective rate. So: cut the work.
//  (1) per-gt-box IoU bounds/area precomputed ONCE, shared by all 3 anchors
//      (bit-identical values; saves ~110 instrs/lane)
//  (2) matched box+class via single dynamic LDS reads (R5-validated) instead
//      of 3x 35-instr cndmask select chains (saves ~95 instrs/lane)
// Everything else = R2 structure (best measured).
__global__ __launch_bounds__(256) void yolo_loss_kernel(
    const float* __restrict__ pred,       // [B,3,8]  row = 24 floats
    const float* __restrict__ gt_boxes,   // [B,8,4]  row = 32 floats
    const int*   __restrict__ gt_classes, // [B,8]    row = 8 ints
    double* __restrict__ part) {          // [NWAVE] per-wave partials
    // Per-wave [64][16] float4 rows: slots 0-5 pred, 6-13 gt, 14-15 classes.
    // XOR slot swizzle s^(row&15): 16-B aligned b128 ops, banks spread.
    // 64 KB/block -> 2 blocks/CU (R0/R5 proved occupancy is a non-factor here).
    __shared__ float4 sBuf[4][64][16];

    const int tid  = threadIdx.x;
    const int wave = tid >> 6;
    const int lane = tid & 63;
    const int wid  = blockIdx.x * 4 + wave;
    const int wb   = wid * 64;            // wave's batch base

    // ---- coalesced global loads (1 KB/instr), unchanged from R2 ----
    const float4* pA = reinterpret_cast<const float4*>(pred     + (size_t)wb * 24);
    const float4* gA = reinterpret_cast<const float4*>(gt_boxes + (size_t)wb * 32);
    float4 vp[6], vg[8];
    #pragma unroll
    for (int k = 0; k < 6; ++k) vp[k] = pA[k * 64 + lane];
    #pragma unroll
    for (int k = 0; k < 8; ++k) vg[k] = gA[k * 64 + lane];
    const int4* cme = reinterpret_cast<const int4*>(gt_classes + (size_t)(wb + lane) * 8);
    const int4 c0 = cme[0], c1 = cme[1];

    float4 (*buf)[16] = sBuf[wave];
    const unsigned rx = lane & 15;        // this lane's row XOR key

    // ---- stage into LDS (wave-private rows; DS unit in-order per wave) ----
    #pragma unroll
    for (int k = 0; k < 6; ++k) {
        const unsigned f = k * 64 + lane, bl = f / 6u, of = f % 6u;
        buf[bl][of ^ (bl & 15u)] = vp[k];
    }
    #pragma unroll
    for (int k = 0; k < 8; ++k) {
        const unsigned f = k * 64 + lane, bl = f >> 3, of = f & 7;
        buf[bl][(6 + of) ^ (bl & 15u)] = vg[k];
    }
    buf[lane][14 ^ rx] = make_float4(__int_as_float(c0.x), __int_as_float(c0.y),
                                     __int_as_float(c0.z), __int_as_float(c0.w));
    buf[lane][15 ^ rx] = make_float4(__int_as_float(c1.x), __int_as_float(c1.y),
                                     __int_as_float(c1.z), __int_as_float(c1.w));

    const float4* row  = buf[lane];
    const float*  rowf = reinterpret_cast<const float*>(row);

    // ---- per-box precompute, ONCE per batch, shared across all 3 anchors.
    //      Bit-identical to the old per-anchor values (same op order). ----
    float bx1[8], bx2[8], by1[8], by2[8], bar[8];
    #pragma unroll
    for (int n = 0; n < 8; ++n) {
        const float4 g = row[(6 + n) ^ rx];
        const float hw = g.z * 0.5f, hh = g.w * 0.5f;
        bx1[n] = g.x - hw;  bx2[n] = g.x + hw;
        by1[n] = g.y - hh;  by2[n] = g.y + hh;
        bar[n] = g.z * g.w;
    }

    // ---- per-anchor loss math (unrolled: bx1..bar must index statically) ----
    float total = 0.0f;
    #pragma unroll
    for (int a = 0; a < 3; ++a) {
        const float4 q0 = row[(2 * a)     ^ rx];   // p[0..3]
        const float4 q1 = row[(2 * a + 1) ^ rx];   // p[4..7]
        const float px = frcp(1.0f + __expf(-q0.x));
        const float py = frcp(1.0f + __expf(-q0.y));
        const float pw = q0.z;
        const float ph = q0.w;
        const float z  = q1.x;
        const float px1 = px - pw * 0.5f, px2 = px + pw * 0.5f;
        const float py1 = py - ph * 0.5f, py2 = py + ph * 0.5f;
        const float pa_eps = (px2 - px1) * (py2 - py1) + 1e-6f;

        float best_iou = -3.4e38f;
        int best_idx = 0;
        #pragma unroll
        for (int n = 0; n < 8; ++n) {
            const float iw = fmaxf(fminf(px2, bx2[n]) - fmaxf(px1, bx1[n]), 0.0f);
            const float ih = fmaxf(fminf(py2, by2[n]) - fmaxf(py1, by1[n]), 0.0f);
            const float inter = iw * ih;
            const float iou = inter * frcp((pa_eps + bar[n]) - inter);
            const bool upd = iou > best_iou;       // strict > == first-max (argmax)
            best_iou = upd ? iou : best_iou;
            best_idx = upd ? n : best_idx;
        }
        const bool matched = best_iou > 0.5f;

        // matched box + class: single dynamic LDS reads (R5-validated numerics)
        const float4 mb = row[(6 + best_idx) ^ rx];
        const int cslot = (14 + (best_idx >> 2)) ^ rx;
        const int mcls  = __float_as_int(rowf[cslot * 4 + (best_idx & 3)]);

        // conf loss via shared softplus (clamped):
        const float az = fabsf(z);
        const float c  = __logf(1.0f + __expf(-az));
        const float sp_pos = fmaxf(z, 0.0f) + c;
        const float sp_neg = fmaxf(-z, 0.0f) + c;
        total += fminf(matched ? sp_neg : sp_pos, 100.0f);

        if (matched) {
            const float dx = px - mb.x, dy = py - mb.y;
            const float dw = pw - mb.z, dh = ph - mb.w;
            total += 5.0f * (dx*dx + dy*dy + dw*dw + dh*dh);
            const float l0 = q1.y, l1 = q1.z, l2 = q1.w;
            const float m = fmaxf(l0, fmaxf(l1, l2));
            const float lse = m + __logf(__expf(l0-m) + __expf(l1-m) + __expf(l2-m));
            const float sel = (mcls == 0) ? l0 : ((mcls == 1) ? l1 : l2);
            total += lse - sel;
        }
    }

    // ---- wave(64) shuffle reduce -> per-wave partial (no atomics) ----
    #pragma unroll
    for (int off = 32; off > 0; off >>= 1)
        total += __shfl_down(total, off, 64);
    if (lane == 0)
        part[wid] = (double)total;
}

__global__ __launch_bounds__(256) void yolo_reduce_kernel(
    const double* __restrict__ part, float* __restrict__ out) {
    double s = 0.0;
    #pragma unroll 8
    for (int k = 0; k < NWAVE / 256; ++k)
        s += part[threadIdx.x + k * 256];      // coalesced
    #pragma unroll
    for (int off = 32; off > 0; off >>= 1)
        s += __shfl_down(s, off, 64);
    __shared__ double r[4];
    const int lane = threadIdx.x & 63;
    const int wave = threadIdx.x >> 6;
    if (lane == 0) r[wave] = s;
    __syncthreads();
    if (threadIdx.x == 0)
        out[0] = (float)((r[0] + r[1] + r[2] + r[3]) / (double)B_SIZE);
}

extern "C" void kernel_launch(void* const* d_in, const int* in_sizes, int n_in,
                              void* d_out, int out_size, void* d_ws, size_t ws_size,
                              hipStream_t stream) {
    const float* pred       = (const float*)d_in[0];
    const float* gt_boxes   = (const float*)d_in[1];
    const int*   gt_classes = (const int*)d_in[2];
    float* out   = (float*)d_out;
    double* part = (double*)d_ws;   // 16384 doubles = 128 KB scratch; every slot
                                    // written each launch (poison-safe)

    yolo_loss_kernel<<<NBLK, 256, 0, stream>>>(pred, gt_boxes, gt_classes, part);
    yolo_reduce_kernel<<<1, 256, 0, stream>>>(part, out);
}